// Round 7
// baseline (245.582 us; speedup 1.0000x reference)
//
#include <hip/hip_runtime.h>
#include <math.h>

// IDMForwardSim R7: occupancy restructure. 512 blocks x 896 thr (14 waves), NB=16,
// 28 waves/CU. Wave w owns 2 N-tiles; z exchanged via transposed LDS zT (b128 write,
// b64 read); gates j-major over all 896 threads (2 elems each); 2 barriers/step.
// idm_s/noise staged to LDS; tail chain LDS-only; coalesced float4 out store.

#define B_TOT 8192
#define T_STEPS 40
#define NB 16

typedef _Float16 f16;
typedef f16 f16x8 __attribute__((ext_vector_type(8)));
typedef float f32x4 __attribute__((ext_vector_type(4)));

__device__ __forceinline__ float rcpf(float x) { return __builtin_amdgcn_rcpf(x); }
__device__ __forceinline__ float ex2(float x)  { return __builtin_amdgcn_exp2f(x); }
__device__ __forceinline__ float sigf(float x)  { return rcpf(1.f + ex2(-1.44269504f * x)); }
__device__ __forceinline__ float tanhf_(float x){ return fmaf(-2.f, rcpf(1.f + ex2(2.88539008f * x)), 1.f); }

// ws layout (bytes): whb f16[65536] @0 | wxb f16[65536] @131072 | bp f32[512] @262144
//   | awb f16[2048] @264192

__global__ __launch_bounds__(256) void idm_prep(
    const float* __restrict__ Wx, const float* __restrict__ Wh,
    const float* __restrict__ bvec, const float* __restrict__ attw,
    f16* __restrict__ whb, f16* __restrict__ wxb,
    float* __restrict__ bp, f16* __restrict__ awb)
{
  int i = blockIdx.x * 256 + threadIdx.x;  // 0..65535, i = k*512 + n (coalesced reads)
  int k = i >> 9, n = i & 511;
  int g = n >> 7, j128 = n & 127;
  float vh = 0.f, vx = 0.f;
  if (j128 < 100) {
    int col = g * 100 + j128;
    if (k < 100)      { vh = Wh[k * 400 + col]; vx = Wx[k * 400 + col]; }
    else if (k < 102) { vh = Wx[k * 400 + col]; }  // sdv rows folded into Wh-pad
  }
  // dest B-frag index: tile=n>>4, kf=k>>5, l=((k>>3)&3)*16+(n&15), j=k&7
  int idx = (((n >> 4) * 4 + (k >> 5)) * 64 + (((k >> 3) & 3) * 16 + (n & 15))) * 8 + (k & 7);
  whb[idx] = (f16)vh;
  wxb[idx] = (f16)vx;
  if (i < 512) { int gg = i >> 7, jj = i & 127; bp[i] = (jj < 100) ? bvec[gg * 100 + jj] : 0.f; }
  if (i < 2048) {  // awb: B-frag tile with col0 = att_W, cols 1..15 = 0
    int j = i & 7, l = (i >> 3) & 63, kf = i >> 9;
    int kk = kf * 32 + ((l >> 4) & 3) * 8 + j;
    int col = l & 15;
    awb[i] = (f16)((col == 0 && kk < 100) ? attw[kk] : 0.f);
  }
}

__global__ __launch_bounds__(896, 7) void idm_main(
    const float* __restrict__ z_att,
    const float* __restrict__ linear_W,
    const float* __restrict__ linear_b,
    const float* __restrict__ sdv_acts,
    const f16* __restrict__ whb, const f16* __restrict__ wxb,
    const float* __restrict__ bp, const f16* __restrict__ awbg,
    const float* __restrict__ idm_params,
    const float* __restrict__ idm_s,
    const float* __restrict__ att_b,
    const float* __restrict__ noise_f,
    const float* __restrict__ noise_m,
    float* __restrict__ out)
{
  __shared__ f16   hS[16][136];          // [batch][k] 0..99 h, 100..101 sdv, pad 0
  __shared__ float zT[496][20];          // z transposed: [col][batch(+pad)]
  __shared__ float logitS[T_STEPS][16];
  __shared__ f16   sdvS[T_STEPS][16][2];
  __shared__ float sS[16][T_STEPS][6];   // idm_s fields 1,2,4,5,6,7
  __shared__ float nS[2][T_STEPS][16];   // noise_f / noise_m
  __shared__ float accS[2][16][T_STEPS]; // act, att
  __shared__ f16   awbS[2048];           // att_W B-frags

  const int tid = threadIdx.x;
  const int w  = tid >> 6;   // 0..13
  const int l  = tid & 63;
  const int lr = l & 15;
  const int lq = l >> 4;
  const int b0g = blockIdx.x * NB;
  // tile assignment: 28 real tiles T = 8g + r (r in [0,7)); wave w -> indices 2w, 2w+1
  const int i1 = 2 * w, i2 = 2 * w + 1;
  const int T1 = (i1 / 7) * 8 + (i1 % 7);
  const int T2 = (i2 / 7) * 8 + (i2 % 7);
  // gate role: 2 elements (gb, gj), (gb+1, gj)
  const int gj = tid >> 3;        // 0..111
  const int gb = (tid & 7) * 2;   // even batch

  // ---- init + coalesced staging ----
  for (int idx = tid; idx < 1088; idx += 896) ((unsigned*)hS)[idx] = 0u;
  for (int idx = tid; idx < 1280; idx += 896) {
    float v = sdv_acts[(size_t)b0g * 80 + idx];
    int b = idx / 80, r = idx - b * 80;
    sdvS[r >> 1][b][r & 1] = (f16)v;
  }
  for (int idx = tid; idx < 5120; idx += 896) {
    int f = idx & 7;
    if (f != 0 && f != 3) {
      int b = idx / 320, rem = idx - b * 320, t = rem >> 3;
      sS[b][t][(f < 3) ? f - 1 : f - 2] = idm_s[(size_t)b0g * 320 + idx];
    }
  }
  for (int idx = tid; idx < 1280; idx += 896) {
    int which = idx >= 640 ? 1 : 0;
    int r = idx - which * 640;
    int t = r >> 4, i = r & 15;
    nS[which][t][i] = which ? noise_m[(size_t)t * B_TOT + b0g + i]
                            : noise_f[(size_t)t * B_TOT + b0g + i];
  }
  for (int idx = tid; idx < 1024; idx += 896) ((unsigned*)awbS)[idx] = ((const unsigned*)awbg)[idx];
  __syncthreads();

  // ---- phase A: h0 = att_proj, sdv_0 ----
  if (tid < 256) {
    int b = tid >> 4, oct = tid & 15;
    float za[10];
    #pragma unroll
    for (int t2 = 0; t2 < 10; ++t2) za[t2] = z_att[(b0g + b) * 10 + t2];
    #pragma unroll
    for (int jj = 0; jj < 8; ++jj) {
      int j = oct * 8 + jj;
      if (j < 100) {
        float acc = linear_b[j];
        #pragma unroll
        for (int t2 = 0; t2 < 10; ++t2) acc = fmaf(za[t2], linear_W[t2 * 100 + j], acc);
        hS[b][j] = (f16)acc;
      }
    }
  }
  if (tid < 32) hS[tid >> 1][100 + (tid & 1)] = sdvS[0][tid >> 1][tid & 1];
  __syncthreads();

  // ---- weights: Wx frags -> cx, then Wh frags ----
  f16x8 wbA[4], wbB[4];
  #pragma unroll
  for (int kf = 0; kf < 4; ++kf) {
    wbA[kf] = *(const f16x8*)(wxb + ((size_t)(T1 * 4 + kf) * 64 + l) * 8);
    wbB[kf] = *(const f16x8*)(wxb + ((size_t)(T2 * 4 + kf) * 64 + l) * 8);
  }
  float bpA = bp[T1 * 16 + lr], bpB = bp[T2 * 16 + lr];
  f32x4 cxA = {bpA, bpA, bpA, bpA};
  f32x4 cxB = {bpB, bpB, bpB, bpB};
  #pragma unroll
  for (int kf = 0; kf < 4; ++kf) {
    f16x8 a = *(const f16x8*)(&hS[lr][kf * 32 + lq * 8]);
    cxA = __builtin_amdgcn_mfma_f32_16x16x32_f16(a, wbA[kf], cxA, 0, 0, 0);
    cxB = __builtin_amdgcn_mfma_f32_16x16x32_f16(a, wbB[kf], cxB, 0, 0, 0);
  }
  #pragma unroll
  for (int kf = 0; kf < 4; ++kf) {
    wbA[kf] = *(const f16x8*)(whb + ((size_t)(T1 * 4 + kf) * 64 + l) * 8);
    wbB[kf] = *(const f16x8*)(whb + ((size_t)(T2 * 4 + kf) * 64 + l) * 8);
  }

  // gate state
  float cst0 = 0.f, cst1 = 0.f;
  const bool glive = (gj < 100);
  if (glive) { cst0 = (float)hS[gb][gj]; cst1 = (float)hS[gb + 1][gj]; }

  #pragma unroll 1
  for (int t = 0; t < T_STEPS; ++t) {
    // ---- MFMA phase: z = cx + [h,sdv] @ Wh; wave0: logit MFMA ----
    f32x4 zA = cxA, zB = cxB;
    f32x4 zL = {0.f, 0.f, 0.f, 0.f};
    #pragma unroll
    for (int kf = 0; kf < 4; ++kf) {
      f16x8 a = *(const f16x8*)(&hS[lr][kf * 32 + lq * 8]);
      zA = __builtin_amdgcn_mfma_f32_16x16x32_f16(a, wbA[kf], zA, 0, 0, 0);
      zB = __builtin_amdgcn_mfma_f32_16x16x32_f16(a, wbB[kf], zB, 0, 0, 0);
      if (w == 0) {
        f16x8 af = *(const f16x8*)(awbS + ((size_t)kf * 64 + l) * 8);
        zL = __builtin_amdgcn_mfma_f32_16x16x32_f16(a, af, zL, 0, 0, 0);
      }
    }
    if (w == 0 && t > 0 && lr == 0) {
      #pragma unroll
      for (int r = 0; r < 4; ++r) logitS[t - 1][lq * 4 + r] = zL[r];
    }
    *(f32x4*)&zT[T1 * 16 + lr][lq * 4] = zA;
    *(f32x4*)&zT[T2 * 16 + lr][lq * 4] = zB;
    __syncthreads();  // B1: z visible, all hS reads done

    // ---- gate phase: 2 elements/thread ----
    if (glive) {
      float2 zi = *(const float2*)&zT[0 * 128 + gj][gb];
      float2 zf = *(const float2*)&zT[1 * 128 + gj][gb];
      float2 zg = *(const float2*)&zT[2 * 128 + gj][gb];
      float2 zo = *(const float2*)&zT[3 * 128 + gj][gb];
      float cc0 = fmaf(sigf(zf.x), cst0, sigf(zi.x) * tanhf_(zg.x));
      float hh0 = sigf(zo.x) * tanhf_(cc0);
      float cc1 = fmaf(sigf(zf.y), cst1, sigf(zi.y) * tanhf_(zg.y));
      float hh1 = sigf(zo.y) * tanhf_(cc1);
      cst0 = cc0; cst1 = cc1;
      hS[gb][gj]     = (f16)hh0;
      hS[gb + 1][gj] = (f16)hh1;
    }
    if (t + 1 < T_STEPS && tid < 32)
      hS[tid >> 1][100 + (tid & 1)] = sdvS[t + 1][tid >> 1][tid & 1];
    __syncthreads();  // B2: h_{t+1} visible
  }

  // ---- final logit from h^{(T)} ----
  if (w == 0) {
    f32x4 zL = {0.f, 0.f, 0.f, 0.f};
    #pragma unroll
    for (int kf = 0; kf < 4; ++kf) {
      f16x8 a  = *(const f16x8*)(&hS[lr][kf * 32 + lq * 8]);
      f16x8 af = *(const f16x8*)(awbS + ((size_t)kf * 64 + l) * 8);
      zL = __builtin_amdgcn_mfma_f32_16x16x32_f16(a, af, zL, 0, 0, 0);
    }
    if (lr == 0) {
      #pragma unroll
      for (int r = 0; r < 4; ++r) logitS[T_STEPS - 1][lq * 4 + r] = zL[r];
    }
  }
  __syncthreads();

  // ---- tail: per-batch ego/IDM chain, all operands in LDS ----
  if (tid < 16) {
    int b = b0g + tid;
    const float* P = idm_params + (size_t)b * 5;
    float des_v = P[0], des_tg = P[1], min_jx = P[2], max_a = P[3];
    float inv2s = 0.5f / sqrtf(max_a * P[4]);
    float inv_dv = rcpf(des_v);
    float ego_v = idm_s[(size_t)b * 320 + 0];
    float ego_x = idm_s[(size_t)b * 320 + 3];
    float attb = att_b[0];
    float act = 0.f;
    #pragma unroll 4
    for (int t = 0; t < T_STEPS; ++t) {
      float2 s01 = *(const float2*)&sS[tid][t][0];  // f_v, m_v
      float2 s23 = *(const float2*)&sS[tid][t][2];  // f_x, m_x
      float2 s45 = *(const float2*)&sS[tid][t][4];  // f_ex, m_ex
      float nf = nS[0][t][tid], nm = nS[1][t][tid];
      float lg = attb + logitS[t][tid];
      ego_v += act * 0.1f;
      ego_x += ego_v * 0.1f + act * 0.005f;
      float af_, am_;
      {
        float dx = fminf(fmaxf(s23.x - ego_x, 0.5f), 1000.f);
        float dg = min_jx + fmaxf(0.f, des_tg * ego_v + ego_v * (ego_v - s01.x) * inv2s);
        float r = ego_v * inv_dv; float r2 = r * r; float q = dg * rcpf(dx);
        af_ = fminf(fmaxf(max_a * (1.f - r2 * r2 - q * q), -3.f), 3.f);
      }
      {
        float dx = fminf(fmaxf(s23.y - ego_x, 0.5f), 1000.f);
        float dg = min_jx + fmaxf(0.f, des_tg * ego_v + ego_v * (ego_v - s01.y) * inv2s);
        float r = ego_v * inv_dv; float r2 = r * r; float q = dg * rcpf(dx);
        am_ = fminf(fmaxf(max_a * (1.f - r2 * r2 - q * q), -3.f), 3.f);
      }
      float ef2 = s45.x * af_ + (1.f - s45.x) * nf;
      float em2 = s45.y * am_ + (1.f - s45.y) * nm;
      float att = sigf(5.f * lg);
      act = (1.f - att) * ef2 + att * em2;
      accS[0][tid][t] = act;
      accS[1][tid][t] = att;
    }
  }
  __syncthreads();

  // ---- coalesced output store: 640 floats per output ----
  if (tid < 160) {
    f32x4 va = ((const f32x4*)&accS[0][0][0])[tid];
    f32x4 vt = ((const f32x4*)&accS[1][0][0])[tid];
    *(f32x4*)(out + (size_t)b0g * T_STEPS + tid * 4) = va;
    *(f32x4*)(out + (size_t)B_TOT * T_STEPS + (size_t)b0g * T_STEPS + tid * 4) = vt;
  }
}

extern "C" void kernel_launch(void* const* d_in, const int* in_sizes, int n_in,
                              void* d_out, int out_size, void* d_ws, size_t ws_size,
                              hipStream_t stream) {
  const float* z_att      = (const float*)d_in[0];
  const float* idm_params = (const float*)d_in[2];
  const float* idm_s      = (const float*)d_in[3];
  const float* sdv_acts   = (const float*)d_in[4];
  const float* linear_W   = (const float*)d_in[5];
  const float* linear_b   = (const float*)d_in[6];
  const float* lstm_Wx    = (const float*)d_in[7];
  const float* lstm_Wh    = (const float*)d_in[8];
  const float* lstm_b     = (const float*)d_in[9];
  const float* att_W      = (const float*)d_in[10];
  const float* att_b      = (const float*)d_in[11];
  const float* noise_f    = (const float*)d_in[12];
  const float* noise_m    = (const float*)d_in[13];
  float* out = (float*)d_out;

  f16*   whb = (f16*)d_ws;
  f16*   wxb = (f16*)((char*)d_ws + 131072);
  float* bp  = (float*)((char*)d_ws + 262144);
  f16*   awb = (f16*)((char*)d_ws + 264192);

  idm_prep<<<256, 256, 0, stream>>>(lstm_Wx, lstm_Wh, lstm_b, att_W, whb, wxb, bp, awb);
  idm_main<<<B_TOT / NB, 896, 0, stream>>>(z_att, linear_W, linear_b, sdv_acts,
                                           whb, wxb, bp, awb,
                                           idm_params, idm_s, att_b,
                                           noise_f, noise_m, out);
}

// Round 8
// 177.751 us; speedup vs baseline: 1.3816x; 1.3816x over previous
//
#include <hip/hip_runtime.h>
#include <math.h>

// IDMForwardSim R8: R6 K-loop + (a) attention logit folded into Wh-pad column
// n=100 (z col 100 = h.att_W, extracted by wave 6 lr==4 — no separate logit MFMA),
// (b) tail inputs staged to LDS (coalesced), outputs via LDS + coalesced f32x4.
// 512 blocks x 448 thr (7 waves, 2 blocks/CU = 14 waves/CU residency ceiling with
// weights-in-registers). One barrier per step, double-buffered hS.

#define B_TOT 8192
#define T_STEPS 40
#define NB 16

typedef _Float16 f16;
typedef f16 f16x8 __attribute__((ext_vector_type(8)));
typedef float f32x4 __attribute__((ext_vector_type(4)));

__device__ __forceinline__ float rcpf(float x) { return __builtin_amdgcn_rcpf(x); }
__device__ __forceinline__ float ex2(float x)  { return __builtin_amdgcn_exp2f(x); }
__device__ __forceinline__ float sigf(float x)  { return rcpf(1.f + ex2(-1.44269504f * x)); }
__device__ __forceinline__ float tanhf_(float x){ return fmaf(-2.f, rcpf(1.f + ex2(2.88539008f * x)), 1.f); }

// ws layout (bytes): whb f16[65536] @0 | wxb f16[65536] @131072 | bp f32[512] @262144

__global__ __launch_bounds__(256) void idm_prep(
    const float* __restrict__ Wx, const float* __restrict__ Wh,
    const float* __restrict__ bvec, const float* __restrict__ attw,
    f16* __restrict__ whb, f16* __restrict__ wxb,
    float* __restrict__ bp)
{
  int i = blockIdx.x * 256 + threadIdx.x;  // 0..65535, i = k*512 + n (coalesced reads)
  int k = i >> 9, n = i & 511;
  int g = n >> 7, j128 = n & 127;
  float vh = 0.f, vx = 0.f;
  if (j128 < 100) {
    int col = g * 100 + j128;
    if (k < 100)      { vh = Wh[k * 400 + col]; vx = Wx[k * 400 + col]; }
    else if (k < 102) { vh = Wx[k * 400 + col]; }  // sdv rows folded into Wh-pad
  } else if (n == 100 && k < 100) {
    vh = attw[k];  // logit column: z[n=100] = h . att_W (Wx col / bias stay 0)
  }
  // dest B-frag index: tile=n>>4, kf=k>>5, l=((k>>3)&3)*16+(n&15), j=k&7
  int idx = (((n >> 4) * 4 + (k >> 5)) * 64 + (((k >> 3) & 3) * 16 + (n & 15))) * 8 + (k & 7);
  whb[idx] = (f16)vh;
  wxb[idx] = (f16)vx;
  if (i < 512) { int gg = i >> 7, jj = i & 127; bp[i] = (jj < 100) ? bvec[gg * 100 + jj] : 0.f; }
}

__global__ __launch_bounds__(448, 4) void idm_main(
    const float* __restrict__ z_att,
    const float* __restrict__ linear_W,
    const float* __restrict__ linear_b,
    const float* __restrict__ sdv_acts,
    const f16* __restrict__ whb, const f16* __restrict__ wxb,
    const float* __restrict__ bp,
    const float* __restrict__ idm_params,
    const float* __restrict__ idm_s,
    const float* __restrict__ att_b,
    const float* __restrict__ noise_f,
    const float* __restrict__ noise_m,
    float* __restrict__ out)
{
  __shared__ f16   hS[2][16][136];       // [buf][batch][k] 0..99 h, 100..101 sdv, pad 0
  __shared__ f16   sdvS[T_STEPS][16][2];
  __shared__ float logitS[T_STEPS][16];
  __shared__ float sS[16][T_STEPS][6];   // idm_s fields 1,2,4,5,6,7
  __shared__ float nS[2][T_STEPS][16];   // noise_f / noise_m
  __shared__ float accS[2][16][T_STEPS]; // act, att

  const int tid = threadIdx.x;
  const int w  = tid >> 6;   // 0..6 j-tile
  const int l  = tid & 63;
  const int lr = l & 15;
  const int lq = l >> 4;
  const int b0g = blockIdx.x * NB;
  const int jcol = 16 * w + lr;

  // zero hS (pad rows must stay exact 0)
  for (int idx = tid; idx < 2176; idx += 448) ((unsigned*)hS)[idx] = 0u;
  // coalesced staging: sdv (1280 f), idm_s fields (5120 f), noise (1280 f)
  for (int idx = tid; idx < 1280; idx += 448) {
    float v = sdv_acts[(size_t)b0g * 80 + idx];
    int b = idx / 80, r = idx - b * 80;
    sdvS[r >> 1][b][r & 1] = (f16)v;
  }
  for (int idx = tid; idx < 5120; idx += 448) {
    int f = idx & 7;
    if (f != 0 && f != 3) {
      int b = idx / 320, rem = idx - b * 320, t = rem >> 3;
      sS[b][t][(f < 3) ? f - 1 : f - 2] = idm_s[(size_t)b0g * 320 + idx];
    }
  }
  for (int idx = tid; idx < 1280; idx += 448) {
    int which = idx >= 640 ? 1 : 0;
    int r = idx - which * 640;
    int t = r >> 4, i = r & 15;
    nS[which][t][i] = which ? noise_m[(size_t)t * B_TOT + b0g + i]
                            : noise_f[(size_t)t * B_TOT + b0g + i];
  }
  __syncthreads();

  // h0 = att_proj into hS[0]
  if (tid < 256) {
    int b = tid >> 4, oct = tid & 15;
    float za[10];
    #pragma unroll
    for (int t2 = 0; t2 < 10; ++t2) za[t2] = z_att[(b0g + b) * 10 + t2];
    #pragma unroll
    for (int jj = 0; jj < 8; ++jj) {
      int j = oct * 8 + jj;
      if (j < 100) {
        float acc = linear_b[j];
        #pragma unroll
        for (int t2 = 0; t2 < 10; ++t2) acc = fmaf(za[t2], linear_W[t2 * 100 + j], acc);
        hS[0][b][j] = (f16)acc;
      }
    }
  }
  if (tid < 32) hS[0][tid >> 1][100 + (tid & 1)] = sdvS[0][tid >> 1][tid & 1];
  __syncthreads();

  // Wx frags -> cx, then Wh frags (loop-invariant in regs)
  f16x8 wb[4][4];
  #pragma unroll
  for (int g = 0; g < 4; ++g) {
    int tile = w + 8 * g;
    #pragma unroll
    for (int kf = 0; kf < 4; ++kf)
      wb[g][kf] = *(const f16x8*)(wxb + ((size_t)(tile * 4 + kf) * 64 + l) * 8);
  }
  f32x4 cx[4];
  #pragma unroll
  for (int g = 0; g < 4; ++g) {
    float bpv = bp[(w + 8 * g) * 16 + lr];
    f32x4 c = {bpv, bpv, bpv, bpv};
    cx[g] = c;
  }
  #pragma unroll
  for (int kf = 0; kf < 4; ++kf) {
    f16x8 a = *(const f16x8*)(&hS[0][lr][kf * 32 + lq * 8]);
    #pragma unroll
    for (int g = 0; g < 4; ++g)
      cx[g] = __builtin_amdgcn_mfma_f32_16x16x32_f16(a, wb[g][kf], cx[g], 0, 0, 0);
  }
  #pragma unroll
  for (int g = 0; g < 4; ++g) {
    int tile = w + 8 * g;
    #pragma unroll
    for (int kf = 0; kf < 4; ++kf)
      wb[g][kf] = *(const f16x8*)(whb + ((size_t)(tile * 4 + kf) * 64 + l) * 8);
  }

  float cst[4];
  #pragma unroll
  for (int r = 0; r < 4; ++r) cst[r] = (float)hS[0][lq * 4 + r][jcol];

  int p = 0;
  for (int t = 0; t < T_STEPS; ++t) {
    // A-frags for [h^{(t)}, sdv_t]
    f16x8 a0 = *(const f16x8*)(&hS[p][lr][0  + lq * 8]);
    f16x8 a1 = *(const f16x8*)(&hS[p][lr][32 + lq * 8]);
    f16x8 a2 = *(const f16x8*)(&hS[p][lr][64 + lq * 8]);
    f16x8 a3 = *(const f16x8*)(&hS[p][lr][96 + lq * 8]);
    f32x4 z0 = cx[0], z1 = cx[1], z2 = cx[2], z3 = cx[3];
    z0 = __builtin_amdgcn_mfma_f32_16x16x32_f16(a0, wb[0][0], z0, 0, 0, 0);
    z1 = __builtin_amdgcn_mfma_f32_16x16x32_f16(a0, wb[1][0], z1, 0, 0, 0);
    z2 = __builtin_amdgcn_mfma_f32_16x16x32_f16(a0, wb[2][0], z2, 0, 0, 0);
    z3 = __builtin_amdgcn_mfma_f32_16x16x32_f16(a0, wb[3][0], z3, 0, 0, 0);
    z0 = __builtin_amdgcn_mfma_f32_16x16x32_f16(a1, wb[0][1], z0, 0, 0, 0);
    z1 = __builtin_amdgcn_mfma_f32_16x16x32_f16(a1, wb[1][1], z1, 0, 0, 0);
    z2 = __builtin_amdgcn_mfma_f32_16x16x32_f16(a1, wb[2][1], z2, 0, 0, 0);
    z3 = __builtin_amdgcn_mfma_f32_16x16x32_f16(a1, wb[3][1], z3, 0, 0, 0);
    z0 = __builtin_amdgcn_mfma_f32_16x16x32_f16(a2, wb[0][2], z0, 0, 0, 0);
    z1 = __builtin_amdgcn_mfma_f32_16x16x32_f16(a2, wb[1][2], z1, 0, 0, 0);
    z2 = __builtin_amdgcn_mfma_f32_16x16x32_f16(a2, wb[2][2], z2, 0, 0, 0);
    z3 = __builtin_amdgcn_mfma_f32_16x16x32_f16(a2, wb[3][2], z3, 0, 0, 0);
    z0 = __builtin_amdgcn_mfma_f32_16x16x32_f16(a3, wb[0][3], z0, 0, 0, 0);
    z1 = __builtin_amdgcn_mfma_f32_16x16x32_f16(a3, wb[1][3], z1, 0, 0, 0);
    z2 = __builtin_amdgcn_mfma_f32_16x16x32_f16(a3, wb[2][3], z2, 0, 0, 0);
    z3 = __builtin_amdgcn_mfma_f32_16x16x32_f16(a3, wb[3][3], z3, 0, 0, 0);

    // logit for output t-1: z col n=100 (tile 6 = wave 6 g=0, lane lr==4)
    if (w == 6 && t > 0 && lr == 4) {
      #pragma unroll
      for (int r = 0; r < 4; ++r) logitS[t - 1][lq * 4 + r] = z0[r];
    }

    // gates: 4 elements/lane (batch=lq*4+r, j=jcol), clamp-free
    #pragma unroll
    for (int r = 0; r < 4; ++r) {
      float si = sigf(z0[r]);
      float sf = sigf(z1[r]);
      float tg = tanhf_(z2[r]);
      float so = sigf(z3[r]);
      float cc = fmaf(sf, cst[r], si * tg);
      float hh = so * tanhf_(cc);
      cst[r] = cc;
      if (jcol < 100) hS[p ^ 1][lq * 4 + r][jcol] = (f16)hh;
    }
    if (t + 1 < T_STEPS && tid < 32)
      hS[p ^ 1][tid >> 1][100 + (tid & 1)] = sdvS[t + 1][tid >> 1][tid & 1];
    __syncthreads();  // single barrier per step
    p ^= 1;
  }

  // final logit (t = T-1) from h^{(T)} in hS[p]: 4 MFMA on wave 6's gate-0 tile
  if (w == 6) {
    f32x4 zL = {0.f, 0.f, 0.f, 0.f};
    #pragma unroll
    for (int kf = 0; kf < 4; ++kf) {
      f16x8 a = *(const f16x8*)(&hS[p][lr][kf * 32 + lq * 8]);
      zL = __builtin_amdgcn_mfma_f32_16x16x32_f16(a, wb[0][kf], zL, 0, 0, 0);
    }
    if (lr == 4) {
      #pragma unroll
      for (int r = 0; r < 4; ++r) logitS[T_STEPS - 1][lq * 4 + r] = zL[r];
    }
  }
  __syncthreads();

  // ---- tail: per-batch ego/IDM chain, all per-step operands in LDS ----
  if (tid < 16) {
    int b = b0g + tid;
    const float* P = idm_params + (size_t)b * 5;
    float des_v = P[0], des_tg = P[1], min_jx = P[2], max_a = P[3];
    float inv2s = 0.5f / sqrtf(max_a * P[4]);
    float inv_dv = rcpf(des_v);
    float ego_v = idm_s[(size_t)b * 320 + 0];
    float ego_x = idm_s[(size_t)b * 320 + 3];
    float attb = att_b[0];
    float act = 0.f;
    #pragma unroll 4
    for (int t = 0; t < T_STEPS; ++t) {
      float2 s01 = *(const float2*)&sS[tid][t][0];  // f_v, m_v
      float2 s23 = *(const float2*)&sS[tid][t][2];  // f_x, m_x
      float2 s45 = *(const float2*)&sS[tid][t][4];  // f_ex, m_ex
      float nf = nS[0][t][tid], nm = nS[1][t][tid];
      float lg = attb + logitS[t][tid];
      ego_v += act * 0.1f;
      ego_x += ego_v * 0.1f + act * 0.005f;
      float af_, am_;
      {
        float dx = fminf(fmaxf(s23.x - ego_x, 0.5f), 1000.f);
        float dg = min_jx + fmaxf(0.f, des_tg * ego_v + ego_v * (ego_v - s01.x) * inv2s);
        float r = ego_v * inv_dv; float r2 = r * r; float q = dg * rcpf(dx);
        af_ = fminf(fmaxf(max_a * (1.f - r2 * r2 - q * q), -3.f), 3.f);
      }
      {
        float dx = fminf(fmaxf(s23.y - ego_x, 0.5f), 1000.f);
        float dg = min_jx + fmaxf(0.f, des_tg * ego_v + ego_v * (ego_v - s01.y) * inv2s);
        float r = ego_v * inv_dv; float r2 = r * r; float q = dg * rcpf(dx);
        am_ = fminf(fmaxf(max_a * (1.f - r2 * r2 - q * q), -3.f), 3.f);
      }
      float ef2 = s45.x * af_ + (1.f - s45.x) * nf;
      float em2 = s45.y * am_ + (1.f - s45.y) * nm;
      float att = sigf(5.f * lg);
      act = (1.f - att) * ef2 + att * em2;
      accS[0][tid][t] = act;
      accS[1][tid][t] = att;
    }
  }
  __syncthreads();

  // coalesced output store: 640 floats per output
  if (tid < 160) {
    f32x4 va = ((const f32x4*)&accS[0][0][0])[tid];
    f32x4 vt = ((const f32x4*)&accS[1][0][0])[tid];
    *(f32x4*)(out + (size_t)b0g * T_STEPS + tid * 4) = va;
    *(f32x4*)(out + (size_t)B_TOT * T_STEPS + (size_t)b0g * T_STEPS + tid * 4) = vt;
  }
}

extern "C" void kernel_launch(void* const* d_in, const int* in_sizes, int n_in,
                              void* d_out, int out_size, void* d_ws, size_t ws_size,
                              hipStream_t stream) {
  const float* z_att      = (const float*)d_in[0];
  const float* idm_params = (const float*)d_in[2];
  const float* idm_s      = (const float*)d_in[3];
  const float* sdv_acts   = (const float*)d_in[4];
  const float* linear_W   = (const float*)d_in[5];
  const float* linear_b   = (const float*)d_in[6];
  const float* lstm_Wx    = (const float*)d_in[7];
  const float* lstm_Wh    = (const float*)d_in[8];
  const float* lstm_b     = (const float*)d_in[9];
  const float* att_W      = (const float*)d_in[10];
  const float* att_b      = (const float*)d_in[11];
  const float* noise_f    = (const float*)d_in[12];
  const float* noise_m    = (const float*)d_in[13];
  float* out = (float*)d_out;

  f16*   whb = (f16*)d_ws;
  f16*   wxb = (f16*)((char*)d_ws + 131072);
  float* bp  = (float*)((char*)d_ws + 262144);

  idm_prep<<<256, 256, 0, stream>>>(lstm_Wx, lstm_Wh, lstm_b, att_W, whb, wxb, bp);
  idm_main<<<B_TOT / NB, 448, 0, stream>>>(z_att, linear_W, linear_b, sdv_acts,
                                           whb, wxb, bp,
                                           idm_params, idm_s, att_b,
                                           noise_f, noise_m, out);
}